// Round 9
// baseline (147.919 us; speedup 1.0000x reference)
//
#include <hip/hip_runtime.h>

#define DD 256   // feature dim
#define N1 512
#define N2 512
#define BB 4

// Packed fp32 via <2 x float> vector IR -> v_pk_*_f32 (R5 taught us: never
// hand-write VOP3P inline asm).
typedef float f2 __attribute__((ext_vector_type(2)));

// ---------------------------------------------------------------------------
// Kernel 1: projection GEMMs — exact R7 version (best measured total).
// 32(m) x 64(n) tile / 256 threads / 2x4 register blocking, K-chunks of 32,
// register-prefetch double buffering. 512 blocks = 2 blocks/CU.
// ---------------------------------------------------------------------------
__global__ __launch_bounds__(256) void proj_kernel(
    const float* __restrict__ x, const float* __restrict__ y,
    const float* __restrict__ W1, const float* __restrict__ b1,
    float* __restrict__ xp, float* __restrict__ yp)
{
    const int which = blockIdx.z;
    const float* __restrict__ A  = which ? y : x;
    const float* __restrict__ Bw = W1 + which * DD * DD;
    float* __restrict__ outp = which ? yp : xp;

    __shared__ float As[32 * 36];   // As[k][m] (transposed), stride 36
    __shared__ float Bs[32 * 68];   // Bs[k][n], stride 68

    const int tid = threadIdx.x;
    const int tx = tid & 15, ty = tid >> 4;
    const int mBase = blockIdx.x * 32;
    const int nBase = blockIdx.y * 64;

    const float4* A4 = (const float4*)A;
    const float4* B4 = (const float4*)Bw;

    const int ar = tid >> 3;       // 0..31  A row (m)
    const int ac = tid & 7;        // 0..7   A float4 col (k/4)
    const int br = tid >> 4;       // 0..15  B k-row (and +16)
    const int bc = tid & 15;       // 0..15  B float4 col (n/4)

    float4 pa, pb0, pb1;
    pa  = A4[(mBase + ar) * 64 + ac];
    pb0 = B4[br * 64 + (nBase >> 2) + bc];
    pb1 = B4[(br + 16) * 64 + (nBase >> 2) + bc];

    float acc[2][4] = {};

    for (int kc = 0; kc < 8; ++kc) {
        __syncthreads();
        {
            float av[4] = {pa.x, pa.y, pa.z, pa.w};
            #pragma unroll
            for (int q = 0; q < 4; ++q) As[(ac * 4 + q) * 36 + ar] = av[q];
            *(float4*)&Bs[br * 68 + bc * 4] = pb0;
            *(float4*)&Bs[(br + 16) * 68 + bc * 4] = pb1;
        }
        __syncthreads();
        if (kc < 7) {
            pa  = A4[(mBase + ar) * 64 + (kc + 1) * 8 + ac];
            pb0 = B4[((kc + 1) * 32 + br) * 64 + (nBase >> 2) + bc];
            pb1 = B4[((kc + 1) * 32 + br + 16) * 64 + (nBase >> 2) + bc];
        }
        #pragma unroll
        for (int k = 0; k < 32; ++k) {
            float2 a = *(const float2*)&As[k * 36 + ty * 2];
            float4 b = *(const float4*)&Bs[k * 68 + tx * 4];
            float av[2] = {a.x, a.y};
            float bv[4] = {b.x, b.y, b.z, b.w};
            #pragma unroll
            for (int i = 0; i < 2; ++i)
                #pragma unroll
                for (int j = 0; j < 4; ++j)
                    acc[i][j] = fmaf(av[i], bv[j], acc[i][j]);
        }
    }

    float4 bias = make_float4(0.f, 0.f, 0.f, 0.f);
    if (which == 0) bias = *((const float4*)b1 + (nBase >> 2) + tx);
    #pragma unroll
    for (int i = 0; i < 2; ++i) {
        float4 o;
        o.x = acc[i][0] + bias.x;
        o.y = acc[i][1] + bias.y;
        o.z = acc[i][2] + bias.z;
        o.w = acc[i][3] + bias.w;
        ((float4*)outp)[(mBase + ty * 2 + i) * (DD / 4) + (nBase >> 2) + tx] = o;
    }
}

// ---------------------------------------------------------------------------
// Packed tanh-form gelu pair (same math since R2, absmax 3.9e-3):
//   gelu(h) = h * (1 - 1/(exp2(h*(K1 + K2 h^2)) + 1))
// ---------------------------------------------------------------------------
__device__ __forceinline__ f2 gelu2(f2 h)
{
    f2 h2 = h * h;
    f2 t  = __builtin_elementwise_fma(h2, (f2)0.1029432f, (f2)2.3022083f);
    f2 z  = h * t;
    f2 e;
    e.x = __builtin_amdgcn_exp2f(z.x);
    e.y = __builtin_amdgcn_exp2f(z.y);
    f2 a = e + 1.0f;
    f2 r;
    r.x = __builtin_amdgcn_rcpf(a.x);
    r.y = __builtin_amdgcn_rcpf(a.y);
    return __builtin_elementwise_fma(-h, r, h);   // h - h*r = h*sigmoid(z)
}

// ---------------------------------------------------------------------------
// Kernel 2: o[b,n,m] = sum_d gelu(xp[b,n,d] + yp[b,m,d]) * W2[d] + b2
// 32x32 tile / 256-thread (4-wave) block / 2x2 outputs/thread.
// R9 vs R8:
//  - 2 d-chunks of 128 (4 barriers total, was 8) -> longer barrier-free
//    windows so waves desync and trans/pk bursts interleave across waves;
//  - c4 processed in groups of 4 with ALL 16 ds_read_b128 hoisted into
//    arrays before the group's compute (real load-ahead; R8's depth-1
//    version was rolled back by the register allocator at VGPR=40);
//  - __launch_bounds__(256,4) caps VGPR at 128 => still 4 waves/SIMD,
//    4 blocks/CU (LDS 33.8 KB).
// LDS row stride 132 floats: xr reads 16-lane broadcast, yr reads 2-way
// aliased (free, m136). Staging writes are 8-way aliased but only 16 per
// thread total (<1% of cycles) — accepted.
// ---------------------------------------------------------------------------
__global__ __launch_bounds__(256, 4) void cross_kernel(
    const float* __restrict__ xp, const float* __restrict__ yp,
    const float* __restrict__ W2, const float* __restrict__ b2,
    float* __restrict__ o)
{
    __shared__ float xs[32 * 132];
    __shared__ float ys[32 * 132];

    const int tid   = threadIdx.x;
    const int b     = blockIdx.z;
    const int mBase = blockIdx.x * 32;
    const int nBase = blockIdx.y * 32;
    const int tx = tid & 15;       // m sub-index (cols tx, tx+16)
    const int ty = tid >> 4;       // n sub-index (rows ty, ty+16)

    const float4* xp4 = (const float4*)xp + (b * N1 + nBase) * (DD / 4);
    const float4* yp4 = (const float4*)yp + (b * N2 + mBase) * (DD / 4);
    const float4* __restrict__ W2v = (const float4*)W2;

    // staging: 4 float4 per thread per panel per 128-d chunk
    const int srow = tid >> 3;          // 0..31
    const int sc8  = tid & 7;           // 0..7; cols sc8 + 8t, t=0..3

    float4 px[4], py[4];
    #pragma unroll
    for (int t = 0; t < 4; ++t) {
        px[t] = xp4[srow * 64 + sc8 + 8 * t];
        py[t] = yp4[srow * 64 + sc8 + 8 * t];
    }

    f2 acc[2][2] = {};

    for (int kc = 0; kc < 2; ++kc) {
        __syncthreads();
        #pragma unroll
        for (int t = 0; t < 4; ++t) {
            *(float4*)&xs[srow * 132 + (sc8 + 8 * t) * 4] = px[t];
            *(float4*)&ys[srow * 132 + (sc8 + 8 * t) * 4] = py[t];
        }
        __syncthreads();
        if (kc == 0) {
            #pragma unroll
            for (int t = 0; t < 4; ++t) {
                px[t] = xp4[srow * 64 + 32 + sc8 + 8 * t];
                py[t] = yp4[srow * 64 + 32 + sc8 + 8 * t];
            }
        }

        #pragma unroll
        for (int half = 0; half < 2; ++half) {
            // W2 sub-chunk -> SGPRs (uniform), one burst of 16 float4
            float4 wreg[16];
            #pragma unroll
            for (int i = 0; i < 16; ++i) wreg[i] = W2v[kc * 32 + half * 16 + i];

            #pragma unroll
            for (int g = 0; g < 4; ++g) {
                // hoist the whole group's LDS reads (16 x ds_read_b128)
                float4 xr[4][2], yr[4][2];
                #pragma unroll
                for (int q = 0; q < 4; ++q) {
                    const int cc = half * 16 + g * 4 + q;
                    #pragma unroll
                    for (int i = 0; i < 2; ++i) {
                        xr[q][i] = *(const float4*)&xs[(ty + 16 * i) * 132 + cc * 4];
                        yr[q][i] = *(const float4*)&ys[(tx + 16 * i) * 132 + cc * 4];
                    }
                }
                #pragma unroll
                for (int q = 0; q < 4; ++q) {
                    float4 wv = wreg[g * 4 + q];
                    f2 wlo = {wv.x, wv.y};
                    f2 whi = {wv.z, wv.w};
                    #pragma unroll
                    for (int i = 0; i < 2; ++i) {
                        f2 xlo = {xr[q][i].x, xr[q][i].y};
                        f2 xhi = {xr[q][i].z, xr[q][i].w};
                        #pragma unroll
                        for (int j = 0; j < 2; ++j) {
                            f2 ylo = {yr[q][j].x, yr[q][j].y};
                            f2 yhi = {yr[q][j].z, yr[q][j].w};
                            f2 glo = gelu2(xlo + ylo);
                            acc[i][j] = __builtin_elementwise_fma(glo, wlo, acc[i][j]);
                            f2 ghi = gelu2(xhi + yhi);
                            acc[i][j] = __builtin_elementwise_fma(ghi, whi, acc[i][j]);
                        }
                    }
                }
            }
        }
    }

    const float bias2 = b2[0];
    const size_t base = ((size_t)(b * N1 + nBase)) * N2 + mBase;
    #pragma unroll
    for (int i = 0; i < 2; ++i) {
        #pragma unroll
        for (int j = 0; j < 2; ++j) {
            o[base + (size_t)(ty + 16 * i) * N2 + (tx + 16 * j)] =
                acc[i][j].x + acc[i][j].y + bias2;
        }
    }
}

extern "C" void kernel_launch(void* const* d_in, const int* in_sizes, int n_in,
                              void* d_out, int out_size, void* d_ws, size_t ws_size,
                              hipStream_t stream)
{
    const float* x  = (const float*)d_in[0];
    const float* y  = (const float*)d_in[1];
    const float* W1 = (const float*)d_in[2];
    const float* b1 = (const float*)d_in[3];
    const float* W2 = (const float*)d_in[4];
    const float* b2 = (const float*)d_in[5];
    float* o  = (float*)d_out;
    float* xp = (float*)d_ws;                 // 2048*256 floats = 2 MB
    float* yp = xp + (BB * N1) * DD;          // next 2 MB

    dim3 g1(64, 4, 2);               // (M/32, N/64, which) = 512 blocks
    proj_kernel<<<g1, 256, 0, stream>>>(x, y, W1, b1, xp, yp);

    dim3 g2(N2 / 32, N1 / 32, BB);   // 16 x 16 x 4 = 1024 four-wave blocks
    cross_kernel<<<g2, 256, 0, stream>>>(xp, yp, W2, b2, o);
}